// Round 6
// baseline (281.796 us; speedup 1.0000x reference)
//
#include <hip/hip_runtime.h>

// EdgeLoss: mean(|sobel_x(sr)-sobel_x(hr)| + |sobel_y(sr)-sobel_y(hr)|)
// = mean(|sobel_x(d)| + |sobel_y(d)|), d = sr - hr (conv linearity; abs
// erases the kernel-flip sign). Separable: s=[1,2,1]*d, t=[1,0,-1]*d
// (horiz); gx = t_{y-1}+2t_y+t_{y+1}, gy = s_{y-1}-s_{y+1} (vert).
//
// R9 (resubmit -- R5 run died to a container-infra error, no data):
// five structures (R4-R8) all pinned at 105-116us with all pipes idle.
// The invariant that fits: per-CU VMEM wave-instruction service
// ~1/105cy (copy ubench: 1024B/100cy = 6.3TB/s). R4/R8 spent HALF their
// VMEM instructions on 2-lane masked halo scalars (8 useful bytes in a
// full slot) -> ~510 B/instr -> ~2.7 TB/s. Fix: every VMEM instruction
// is a full contiguous 1024B dwordx4, and only compulsory ones issue.
// One wave owns a full 1024-wide x 16-row strip; a row = 4 instrs/tensor
// (lane's 16 floats = 4 interleaved float4 chunks at cols q*256+lane*4,
// so each INSTRUCTION is 1024B contiguous). Horizontal halo entirely
// in-register: shfl within chunk + broadcast shuffles across chunk
// boundaries (all lanes execute; cndmask selects). Zero scalar loads,
// zero barriers, zero LDS staging. Vertical reuse in a 3-age s/t
// register window; 18 loads per 16 output rows = 1.125x overfetch.
// 2048 waves x 144 instrs = 295k instrs ~= 1.13x compulsory 262k.
// Floor: 1152 instrs/CU x 105cy ~= 50us.

#define IMG_H 1024
#define IMG_W 1024
#define IMG_B 32
#define R 16                        // output rows per wave-strip
#define SPI (IMG_H / R)             // 64 strips per image
#define NSTRIP (IMG_B * SPI)        // 2048 wave-strips
#define NBLK (NSTRIP / 4)           // 512 blocks x 4 independent waves

struct Row { float4 a[4]; float4 b[4]; };   // full 1024-col row, both tensors

__global__ __launch_bounds__(256, 2) void edge_loss_kernel(
        const float* __restrict__ sr, const float* __restrict__ hr,
        float* __restrict__ out, float invN) {
    const int tid   = threadIdx.x;
    const int lane  = tid & 63;
    const int wv    = tid >> 6;
    const int strip = blockIdx.x * 4 + wv;   // 0..2047, waves independent
    const int b     = strip >> 6;            // image
    const int ys    = strip & 63;            // row-strip in image
    const int y0    = ys * R;                // first output row
    const size_t img = (size_t)b * IMG_H * IMG_W;
    const int col   = lane * 4;              // lane offset within a chunk

    // Load local row l (global row y0-1+l, clamped; zeroed via mask in ST).
    // 8 x global_load_dwordx4, each 1024B contiguous (chunk q = cols
    // [q*256, q*256+255], lane takes 4 floats at q*256+lane*4).
    auto LOAD = [&](int l, Row& r) {
        const int rc = min(max(y0 - 1 + l, 0), IMG_H - 1);
        const float* pa = sr + img + (size_t)rc * IMG_W + col;
        const float* pb = hr + img + (size_t)rc * IMG_W + col;
        #pragma unroll
        for (int q = 0; q < 4; ++q) {
            r.a[q] = *reinterpret_cast<const float4*>(pa + q * 256);
            r.b[q] = *reinterpret_cast<const float4*>(pb + q * 256);
        }
    };

    // Horizontal pass on one row: d=(a-b)*m; s=[1,2,1]*d; t=[1,0,-1]*d.
    // Chunk-boundary halos via cross-lane broadcast of the ADJACENT
    // chunk's register (all lanes execute shuffles; selects are cndmask).
    auto ST = [&](const Row& r, float m, float4* S, float4* T) {
        float4 d[4];
        #pragma unroll
        for (int q = 0; q < 4; ++q) {
            d[q].x = (r.a[q].x - r.b[q].x) * m;
            d[q].y = (r.a[q].y - r.b[q].y) * m;
            d[q].z = (r.a[q].z - r.b[q].z) * m;
            d[q].w = (r.a[q].w - r.b[q].w) * m;
        }
        #pragma unroll
        for (int q = 0; q < 4; ++q) {
            float dl = __shfl_up(d[q].w, 1);        // left neighbor, same chunk
            float dr = __shfl_down(d[q].x, 1);      // right neighbor, same chunk
            // chunk-boundary columns: lane0's left is lane63 of chunk q-1;
            // lane63's right is lane0 of chunk q+1; image edges are zero.
            const float bl = (q > 0) ? __shfl(d[q - 1].w, 63) : 0.f;
            const float br = (q < 3) ? __shfl(d[q + 1].x, 0)  : 0.f;
            if (lane == 0)  dl = bl;
            if (lane == 63) dr = br;
            S[q].x = dl     + 2.f * d[q].x + d[q].y;
            S[q].y = d[q].x + 2.f * d[q].y + d[q].z;
            S[q].z = d[q].y + 2.f * d[q].z + d[q].w;
            S[q].w = d[q].z + 2.f * d[q].w + dr;
            T[q].x = dl     - d[q].y;
            T[q].y = d[q].x - d[q].z;
            T[q].z = d[q].y - d[q].w;
            T[q].w = d[q].z - dr;
        }
    };

    // ---- software pipeline: 2 row buffers, 3-age s/t window ----
    Row b0, b1;
    LOAD(0, b0);
    LOAD(1, b1);

    float4 S[3][4], T[3][4];        // all indices compile-time (unrolled)
    const float mT = (y0 > 0) ? 1.f : 0.f;      // local row 0 = global y0-1
    ST(b0, mT, S[0], T[0]);
    LOAD(2, b0);
    ST(b1, 1.f, S[1], T[1]);        // local row 1 = global y0, always valid
    LOAD(3, b1);

    float acc = 0.f;
    #pragma unroll
    for (int i = 0; i < R; ++i) {                // output row y0+i
        Row& cur = (i & 1) ? b1 : b0;            // holds local row l=i+2
        const int l = i + 2;
        const float m = ((unsigned)(y0 + i + 1) < IMG_H) ? 1.f : 0.f;
        ST(cur, m, S[(i + 2) % 3], T[(i + 2) % 3]);
        if (l + 2 <= R + 1) LOAD(l + 2, cur);    // prefetch next-next row

        #pragma unroll
        for (int q = 0; q < 4; ++q) {
            const float4 t0 = T[i % 3][q];
            const float4 t1 = T[(i + 1) % 3][q];
            const float4 t2 = T[(i + 2) % 3][q];
            const float4 s0 = S[i % 3][q];
            const float4 s2 = S[(i + 2) % 3][q];
            float gx, gy;
            gx = t0.x + 2.f * t1.x + t2.x;  gy = s0.x - s2.x;  acc += fabsf(gx) + fabsf(gy);
            gx = t0.y + 2.f * t1.y + t2.y;  gy = s0.y - s2.y;  acc += fabsf(gx) + fabsf(gy);
            gx = t0.z + 2.f * t1.z + t2.z;  gy = s0.z - s2.z;  acc += fabsf(gx) + fabsf(gy);
            gx = t0.w + 2.f * t1.w + t2.w;  gy = s0.w - s2.w;  acc += fabsf(gx) + fabsf(gy);
        }
    }

    // ---- reduction: wave shuffle -> 16B LDS -> 1 atomic/block ----
    #pragma unroll
    for (int off = 32; off > 0; off >>= 1)
        acc += __shfl_down(acc, off, 64);

    __shared__ float wsum[4];
    if (lane == 0) wsum[wv] = acc;
    __syncthreads();
    if (tid == 0) {
        const float bsum = wsum[0] + wsum[1] + wsum[2] + wsum[3];
        atomicAdd(out, bsum * invN);
    }
}

extern "C" void kernel_launch(void* const* d_in, const int* in_sizes, int n_in,
                              void* d_out, int out_size, void* d_ws, size_t ws_size,
                              hipStream_t stream) {
    const float* sr = (const float*)d_in[0];
    const float* hr = (const float*)d_in[1];
    float* out = (float*)d_out;

    hipMemsetAsync(out, 0, sizeof(float), stream);

    const float invN = 1.0f / (float)((size_t)IMG_B * IMG_H * IMG_W);
    edge_loss_kernel<<<dim3(NBLK), 256, 0, stream>>>(sr, hr, out, invN);
}